// Round 8
// baseline (449.189 us; speedup 1.0000x reference)
//
#include <hip/hip_runtime.h>

#define NN 50000
#define EE 800000
#define CH 128
#define NGR 64
#define NB 196        // ceil(NN/256)

// ---------------------------------------------------------------- CSR build
__global__ __launch_bounds__(256) void count_deg(const int* __restrict__ dst,
                                                 int* __restrict__ counts) {
  int e = blockIdx.x * 256 + threadIdx.x;
  if (e < EE) atomicAdd(&counts[dst[e]], 1);
}

__global__ __launch_bounds__(256) void scan_block_sums(const int* __restrict__ counts,
                                                       int* __restrict__ blockSums) {
  __shared__ int red[256];
  int t = threadIdx.x;
  int i = blockIdx.x * 256 + t;
  red[t] = (i < NN) ? counts[i] : 0;
  __syncthreads();
  for (int off = 128; off > 0; off >>= 1) {
    if (t < off) red[t] += red[t + off];
    __syncthreads();
  }
  if (t == 0) blockSums[blockIdx.x] = red[0];
}

// merged: redundant per-block scan of the 196 block sums (saves a kernel)
__global__ __launch_bounds__(256) void scan_final(const int* __restrict__ counts,
                                                  const int* __restrict__ blockSums,
                                                  int* __restrict__ rowptr,
                                                  int* __restrict__ fillptr,
                                                  float* __restrict__ dinv) {
  __shared__ int tmp[256];
  __shared__ int sOffs[256];
  int t = threadIdx.x;
  int bs = (t < NB) ? blockSums[t] : 0;
  sOffs[t] = bs;
  __syncthreads();
  for (int off = 1; off < 256; off <<= 1) {
    int add = (t >= off) ? sOffs[t - off] : 0;
    __syncthreads();
    sOffs[t] += add;
    __syncthreads();
  }
  // exclusive block offset = inclusive sum at b minus b's own sum
  int myBlockOff = sOffs[blockIdx.x] - blockSums[blockIdx.x];

  int i = blockIdx.x * 256 + t;
  int v = (i < NN) ? counts[i] : 0;
  tmp[t] = v;
  __syncthreads();
  for (int off = 1; off < 256; off <<= 1) {
    int add = (t >= off) ? tmp[t - off] : 0;
    __syncthreads();
    tmp[t] += add;
    __syncthreads();
  }
  if (i < NN) {
    int ex = myBlockOff + tmp[t] - v;
    rowptr[i] = ex;
    fillptr[i] = ex;
    dinv[i] = rsqrtf((float)v + 1.0f);
  }
  if (i == 0) rowptr[NN] = EE;
}

// packed edge record: .x = src node, .y = bitcast(norm)
__global__ __launch_bounds__(256) void fill_csr(const int* __restrict__ src,
                                                const int* __restrict__ dst,
                                                const float* __restrict__ dinv,
                                                int* __restrict__ fillptr,
                                                int2* __restrict__ edges) {
  int e = blockIdx.x * 256 + threadIdx.x;
  if (e >= EE) return;
  int s = src[e], d = dst[e];
  int slot = atomicAdd(&fillptr[d], 1);
  edges[slot] = make_int2(s, __float_as_int(dinv[s] * dinv[d]));
}

// ---------------------------------------------------------------- GEMM 50000x128 @ 128x128
// block = 256 threads, tile = 64 rows x 128 cols, K in 2 halves of 64.
// LDS: sW 32KB (k-half of W) + sX 16KB (64 rows x 64 k) = 48KB -> 3 blocks/CU.
// 8 rows/thread: 12 LDS b128 reads per 128 FMAs (was 16 per 128).
__global__ __launch_bounds__(256) void gemm128(const float* __restrict__ X,
                                               const float* __restrict__ W,
                                               float* __restrict__ H) {
  __shared__ float sW[64 * 128];
  __shared__ float sX[64 * 64];
  float4* sW4 = (float4*)sW;
  float4* sX4 = (float4*)sX;
  const float4* X4 = (const float4*)X;
  const float4* W4 = (const float4*)W;
  int t = threadIdx.x;
  int row0 = blockIdx.x * 64;
  int lane = t & 31;       // col group: cols lane*4 .. lane*4+3
  int rowg = t >> 5;       // row group: rows rowg*8 .. rowg*8+7

  float acc[8][4];
  #pragma unroll
  for (int r = 0; r < 8; ++r)
    #pragma unroll
    for (int c = 0; c < 4; ++c) acc[r][c] = 0.f;

  for (int kt = 0; kt < 2; ++kt) {
    __syncthreads();
    // stage W k-half: 64 k-rows x 128 cols = 2048 f4
    #pragma unroll
    for (int i = 0; i < 8; ++i) {
      int idx = t + 256 * i;
      sW4[idx] = W4[kt * 2048 + idx];
    }
    // stage X k-half: 64 rows x 16 f4 = 1024 f4 (16 threads/row, 256B chunks)
    #pragma unroll
    for (int i = 0; i < 4; ++i) {
      int idx = t + 256 * i;
      int row = row0 + (idx >> 4);
      int c4 = idx & 15;
      float4 v = make_float4(0.f, 0.f, 0.f, 0.f);
      if (row < NN) v = X4[(size_t)row * 32 + kt * 16 + c4];
      sX4[idx] = v;
    }
    __syncthreads();
    #pragma unroll
    for (int k4 = 0; k4 < 16; ++k4) {
      float4 xv[8];
      #pragma unroll
      for (int r = 0; r < 8; ++r)
        xv[r] = sX4[(rowg * 8 + r) * 16 + k4];   // broadcast within 32-lane group
      #pragma unroll
      for (int kk = 0; kk < 4; ++kk) {
        float4 wv = sW4[(k4 * 4 + kk) * 32 + lane];
        #pragma unroll
        for (int r = 0; r < 8; ++r) {
          float xs = (kk == 0) ? xv[r].x : (kk == 1) ? xv[r].y : (kk == 2) ? xv[r].z : xv[r].w;
          acc[r][0] += xs * wv.x;
          acc[r][1] += xs * wv.y;
          acc[r][2] += xs * wv.z;
          acc[r][3] += xs * wv.w;
        }
      }
    }
  }

  #pragma unroll
  for (int r = 0; r < 8; ++r) {
    int row = row0 + rowg * 8 + r;
    if (row < NN)
      ((float4*)H)[(size_t)row * 32 + lane] =
          make_float4(acc[r][0], acc[r][1], acc[r][2], acc[r][3]);
  }
}

// ---------------------------------------------------------------- aggregation + self-loop + bias + tanh
// 1 wave per node: 64 lanes x float2. Cooperative edge-record load, then
// readlane-broadcast -> SGPR-based gathers, 16-deep unroll (MLP discriminator).
__global__ __launch_bounds__(256) void gcn_agg(const float* __restrict__ H,
                                               const int* __restrict__ rowptr,
                                               const int2* __restrict__ edges,
                                               const float* __restrict__ dinv,
                                               const float* __restrict__ bias,
                                               float* __restrict__ out) {
  int nid = blockIdx.x * 4 + (threadIdx.x >> 6);
  if (nid >= NN) return;
  int lane = threadIdx.x & 63;
  const float2* H2 = (const float2*)H;          // row stride = 64 float2
  float di = dinv[nid];
  float sw = di * di;
  float2 self = H2[(size_t)nid * 64 + lane];
  float ax = self.x * sw, ay = self.y * sw;

  int e0 = rowptr[nid], e1 = rowptr[nid + 1];
  for (int c = e0; c < e1; c += 64) {
    // cooperative edge-record load; inactive lanes get {src=0, w=0}
    int2 rec = (c + lane < e1) ? edges[c + lane] : make_int2(0, 0);
    int cnt = e1 - c; if (cnt > 64) cnt = 64;
    int cend = (cnt + 15) & ~15;                // round to unroll width 16
    for (int u = 0; u < cend; u += 16) {
      float2 v[16];
      float wg[16];
      #pragma unroll
      for (int q = 0; q < 16; ++q) {
        int s  = __builtin_amdgcn_readlane(rec.x, u + q);   // SGPR src id
        wg[q]  = __int_as_float(__builtin_amdgcn_readlane(rec.y, u + q));
        v[q]   = H2[(size_t)s * 64 + lane];     // saddr + lane offset gather
      }
      #pragma unroll
      for (int q = 0; q < 16; ++q) {
        ax += v[q].x * wg[q];
        ay += v[q].y * wg[q];
      }
    }
  }

  float2 b = ((const float2*)bias)[lane];
  float2 r;
  r.x = tanhf(ax + b.x);
  r.y = tanhf(ay + b.y);
  ((float2*)out)[(size_t)nid * 64 + lane] = r;
}

// ---------------------------------------------------------------- final linear(128->6)+tanh + mean pool
// 4 threads per node; LDS per-graph accumulators, one flush per block.
__global__ __launch_bounds__(256) void linpool(const float* __restrict__ H,
                                               const float* __restrict__ Wl,
                                               const float* __restrict__ bl,
                                               const int* __restrict__ batch,
                                               float* __restrict__ gsum,
                                               int* __restrict__ gcnt) {
  __shared__ float sW[128 * 6];
  __shared__ float sSum[NGR * 6];
  __shared__ int sCnt[NGR];
  int t = threadIdx.x;
  for (int i = t; i < 768; i += 256) sW[i] = Wl[i];
  for (int i = t; i < NGR * 6; i += 256) sSum[i] = 0.f;
  if (t < NGR) sCnt[t] = 0;
  __syncthreads();

  int gid = blockIdx.x * 256 + t;
  int node = gid >> 2;
  int seg = gid & 3;          // each of 4 threads handles 32 k's
  float a0 = 0, a1 = 0, a2 = 0, a3 = 0, a4 = 0, a5 = 0;
  if (node < NN) {
    const float4* H4 = (const float4*)(H + (size_t)node * 128 + seg * 32);
    #pragma unroll
    for (int q = 0; q < 8; ++q) {
      float4 hv = H4[q];
      float hvv[4] = {hv.x, hv.y, hv.z, hv.w};
      int kbase = seg * 32 + q * 4;
      #pragma unroll
      for (int kk = 0; kk < 4; ++kk) {
        float hx = hvv[kk];
        const float* wr = &sW[(kbase + kk) * 6];
        a0 += hx * wr[0]; a1 += hx * wr[1]; a2 += hx * wr[2];
        a3 += hx * wr[3]; a4 += hx * wr[4]; a5 += hx * wr[5];
      }
    }
  }
  // reduce across the 4 lanes of the node
  a0 += __shfl_xor(a0, 1); a0 += __shfl_xor(a0, 2);
  a1 += __shfl_xor(a1, 1); a1 += __shfl_xor(a1, 2);
  a2 += __shfl_xor(a2, 1); a2 += __shfl_xor(a2, 2);
  a3 += __shfl_xor(a3, 1); a3 += __shfl_xor(a3, 2);
  a4 += __shfl_xor(a4, 1); a4 += __shfl_xor(a4, 2);
  a5 += __shfl_xor(a5, 1); a5 += __shfl_xor(a5, 2);
  if (node < NN && seg == 0) {
    int g = batch[node];
    atomicAdd(&sSum[g * 6 + 0], tanhf(a0 + bl[0]));
    atomicAdd(&sSum[g * 6 + 1], tanhf(a1 + bl[1]));
    atomicAdd(&sSum[g * 6 + 2], tanhf(a2 + bl[2]));
    atomicAdd(&sSum[g * 6 + 3], tanhf(a3 + bl[3]));
    atomicAdd(&sSum[g * 6 + 4], tanhf(a4 + bl[4]));
    atomicAdd(&sSum[g * 6 + 5], tanhf(a5 + bl[5]));
    atomicAdd(&sCnt[g], 1);
  }
  __syncthreads();
  for (int i = t; i < NGR * 6; i += 256) {
    int g = i / 6;
    if (sCnt[g] > 0) atomicAdd(&gsum[i], sSum[i]);
  }
  if (t < NGR && sCnt[t] > 0) atomicAdd(&gcnt[t], sCnt[t]);
}

__global__ void finalize(const float* __restrict__ gsum, const int* __restrict__ gcnt,
                         float* __restrict__ out) {
  int i = threadIdx.x;
  if (i < NGR * 6) {
    int g = i / 6;
    float c = (float)max(gcnt[g], 1);
    out[i] = gsum[i] / c;
  }
}

// ---------------------------------------------------------------- launch
extern "C" void kernel_launch(void* const* d_in, const int* in_sizes, int n_in,
                              void* d_out, int out_size, void* d_ws, size_t ws_size,
                              hipStream_t stream) {
  const float* x  = (const float*)d_in[0];
  const int*   ei = (const int*)d_in[1];     // JAX x64 disabled -> int32
  const int*   batch = (const int*)d_in[2];
  const float* W0 = (const float*)d_in[3];
  const float* b0 = (const float*)d_in[4];
  const float* W1 = (const float*)d_in[5];
  const float* b1 = (const float*)d_in[6];
  const float* W2 = (const float*)d_in[7];
  const float* b2 = (const float*)d_in[8];
  const float* Wl = (const float*)d_in[9];
  const float* bl = (const float*)d_in[10];
  float* out = (float*)d_out;

  const int* src = ei;
  const int* dst = ei + EE;

  char* w = (char*)d_ws;
  auto alloc = [&](size_t bytes) {
    void* p = (void*)w;
    w += (bytes + 255) & ~(size_t)255;
    return p;
  };
  float* bufA   = (float*)alloc((size_t)NN * CH * 4);
  float* bufB   = (float*)alloc((size_t)NN * CH * 4);
  int*   counts = (int*)alloc((size_t)NN * 4);
  int*   rowptr = (int*)alloc((size_t)(NN + 1) * 4);
  int*   fillptr= (int*)alloc((size_t)NN * 4);
  float* dinv   = (float*)alloc((size_t)NN * 4);
  int2*  edges  = (int2*)alloc((size_t)EE * 8);
  int*   blockSums = (int*)alloc(256 * 4);
  float* gsum   = (float*)alloc((NGR * 6 + NGR) * 4);
  int*   gcnt   = (int*)(gsum + NGR * 6);

  hipMemsetAsync(counts, 0, (size_t)NN * 4, stream);
  hipMemsetAsync(gsum, 0, (NGR * 6 + NGR) * 4, stream);

  // CSR build (reused for all 3 layers)
  count_deg<<<(EE + 255) / 256, 256, 0, stream>>>(dst, counts);
  scan_block_sums<<<NB, 256, 0, stream>>>(counts, blockSums);
  scan_final<<<NB, 256, 0, stream>>>(counts, blockSums, rowptr, fillptr, dinv);
  fill_csr<<<(EE + 255) / 256, 256, 0, stream>>>(src, dst, dinv, fillptr, edges);

  const int gemmGrid = (NN + 63) / 64;
  const int aggGrid  = (NN + 3) / 4;

  // layer 0: x -> bufA (h) -> bufB (act)
  gemm128<<<gemmGrid, 256, 0, stream>>>(x, W0, bufA);
  gcn_agg<<<aggGrid, 256, 0, stream>>>(bufA, rowptr, edges, dinv, b0, bufB);
  // layer 1
  gemm128<<<gemmGrid, 256, 0, stream>>>(bufB, W1, bufA);
  gcn_agg<<<aggGrid, 256, 0, stream>>>(bufA, rowptr, edges, dinv, b1, bufB);
  // layer 2
  gemm128<<<gemmGrid, 256, 0, stream>>>(bufB, W2, bufA);
  gcn_agg<<<aggGrid, 256, 0, stream>>>(bufA, rowptr, edges, dinv, b2, bufB);

  // final linear + tanh + mean pool
  linpool<<<(NN * 4 + 255) / 256, 256, 0, stream>>>(bufB, Wl, bl, batch, gsum, gcnt);
  finalize<<<1, NGR * 6, 0, stream>>>(gsum, gcnt, out);
}

// Round 11
// 367.369 us; speedup vs baseline: 1.2227x; 1.2227x over previous
//
#include <hip/hip_runtime.h>
#include <hip/hip_fp16.h>

#define NN 50000
#define EE 800000
#define CH 128
#define NGR 64
#define NB 196        // ceil(NN/256)

// ---------------------------------------------------------------- CSR build
__global__ __launch_bounds__(256) void count_deg(const int* __restrict__ dst,
                                                 int* __restrict__ counts) {
  int e = blockIdx.x * 256 + threadIdx.x;
  if (e < EE) atomicAdd(&counts[dst[e]], 1);
}

__global__ __launch_bounds__(256) void scan_block_sums(const int* __restrict__ counts,
                                                       int* __restrict__ blockSums) {
  __shared__ int red[256];
  int t = threadIdx.x;
  int i = blockIdx.x * 256 + t;
  red[t] = (i < NN) ? counts[i] : 0;
  __syncthreads();
  for (int off = 128; off > 0; off >>= 1) {
    if (t < off) red[t] += red[t + off];
    __syncthreads();
  }
  if (t == 0) blockSums[blockIdx.x] = red[0];
}

// merged: per-block re-scan of the 196 block sums (saves a kernel)
__global__ __launch_bounds__(256) void scan_final(const int* __restrict__ counts,
                                                  const int* __restrict__ blockSums,
                                                  int* __restrict__ rowptr,
                                                  int* __restrict__ fillptr,
                                                  float* __restrict__ dinv) {
  __shared__ int tmp[256];
  __shared__ int sOffs[256];
  int t = threadIdx.x;
  int bs = (t < NB) ? blockSums[t] : 0;
  sOffs[t] = bs;
  __syncthreads();
  for (int off = 1; off < 256; off <<= 1) {
    int add = (t >= off) ? sOffs[t - off] : 0;
    __syncthreads();
    sOffs[t] += add;
    __syncthreads();
  }
  int myBlockOff = sOffs[blockIdx.x] - blockSums[blockIdx.x];

  int i = blockIdx.x * 256 + t;
  int v = (i < NN) ? counts[i] : 0;
  tmp[t] = v;
  __syncthreads();
  for (int off = 1; off < 256; off <<= 1) {
    int add = (t >= off) ? tmp[t - off] : 0;
    __syncthreads();
    tmp[t] += add;
    __syncthreads();
  }
  if (i < NN) {
    int ex = myBlockOff + tmp[t] - v;
    rowptr[i] = ex;
    fillptr[i] = ex;
    dinv[i] = rsqrtf((float)v + 1.0f);
  }
  if (i == 0) rowptr[NN] = EE;
}

// packed edge record: .x = src node, .y = bitcast(norm)
__global__ __launch_bounds__(256) void fill_csr(const int* __restrict__ src,
                                                const int* __restrict__ dst,
                                                const float* __restrict__ dinv,
                                                int* __restrict__ fillptr,
                                                int2* __restrict__ edges) {
  int e = blockIdx.x * 256 + threadIdx.x;
  if (e >= EE) return;
  int s = src[e], d = dst[e];
  int slot = atomicAdd(&fillptr[d], 1);
  edges[slot] = make_int2(s, __float_as_int(dinv[s] * dinv[d]));
}

// ---------------------------------------------------------------- GEMM 50000x128 @ 128x128, fp16 output
// block = 256 threads, tile = 64 rows x 128 cols, K in 2 halves of 64.
// LDS: sW 32KB + sX 16KB = 48KB -> 3 blocks/CU. 8 rows/thread.
// Epilogue packs acc to fp16 (halves h-buffer: gather payload 512B->256B/row).
__global__ __launch_bounds__(256) void gemm128(const float* __restrict__ X,
                                               const float* __restrict__ W,
                                               __half* __restrict__ H16) {
  __shared__ float sW[64 * 128];
  __shared__ float sX[64 * 64];
  float4* sW4 = (float4*)sW;
  float4* sX4 = (float4*)sX;
  const float4* X4 = (const float4*)X;
  const float4* W4 = (const float4*)W;
  int t = threadIdx.x;
  int row0 = blockIdx.x * 64;
  int lane = t & 31;       // col group: cols lane*4 .. lane*4+3
  int rowg = t >> 5;       // row group: rows rowg*8 .. rowg*8+7

  float acc[8][4];
  #pragma unroll
  for (int r = 0; r < 8; ++r)
    #pragma unroll
    for (int c = 0; c < 4; ++c) acc[r][c] = 0.f;

  for (int kt = 0; kt < 2; ++kt) {
    __syncthreads();
    #pragma unroll
    for (int i = 0; i < 8; ++i) {
      int idx = t + 256 * i;
      sW4[idx] = W4[kt * 2048 + idx];
    }
    #pragma unroll
    for (int i = 0; i < 4; ++i) {
      int idx = t + 256 * i;
      int row = row0 + (idx >> 4);
      int c4 = idx & 15;
      float4 v = make_float4(0.f, 0.f, 0.f, 0.f);
      if (row < NN) v = X4[(size_t)row * 32 + kt * 16 + c4];
      sX4[idx] = v;
    }
    __syncthreads();
    #pragma unroll
    for (int k4 = 0; k4 < 16; ++k4) {
      float4 xv[8];
      #pragma unroll
      for (int r = 0; r < 8; ++r)
        xv[r] = sX4[(rowg * 8 + r) * 16 + k4];
      #pragma unroll
      for (int kk = 0; kk < 4; ++kk) {
        float4 wv = sW4[(k4 * 4 + kk) * 32 + lane];
        #pragma unroll
        for (int r = 0; r < 8; ++r) {
          float xs = (kk == 0) ? xv[r].x : (kk == 1) ? xv[r].y : (kk == 2) ? xv[r].z : xv[r].w;
          acc[r][0] += xs * wv.x;
          acc[r][1] += xs * wv.y;
          acc[r][2] += xs * wv.z;
          acc[r][3] += xs * wv.w;
        }
      }
    }
  }

  #pragma unroll
  for (int r = 0; r < 8; ++r) {
    int row = row0 + rowg * 8 + r;
    if (row < NN) {
      __half2 p0 = __floats2half2_rn(acc[r][0], acc[r][1]);
      __half2 p1 = __floats2half2_rn(acc[r][2], acc[r][3]);
      uint2 u = make_uint2(*(unsigned*)&p0, *(unsigned*)&p1);
      ((uint2*)H16)[(size_t)row * 32 + lane] = u;   // 8B at row*256 + lane*8
    }
  }
}

// ---------------------------------------------------------------- aggregation + self-loop + bias + tanh
// 1 wave per node: 64 lanes x half2 (2 channels each). Cooperative edge-record
// load -> readlane-broadcast -> SGPR-base fp16 gathers (256B/row), 16-deep.
__global__ __launch_bounds__(256) void gcn_agg(const __half* __restrict__ H16,
                                               const int* __restrict__ rowptr,
                                               const int2* __restrict__ edges,
                                               const float* __restrict__ dinv,
                                               const float* __restrict__ bias,
                                               float* __restrict__ out) {
  int nid = blockIdx.x * 4 + (threadIdx.x >> 6);
  if (nid >= NN) return;
  int lane = threadIdx.x & 63;
  const __half2* Hh = (const __half2*)H16;      // 64 half2 per row
  float di = dinv[nid];
  float sw = di * di;
  float2 self = __half22float2(Hh[(size_t)nid * 64 + lane]);
  float ax = self.x * sw, ay = self.y * sw;

  int e0 = rowptr[nid], e1 = rowptr[nid + 1];
  for (int c = e0; c < e1; c += 64) {
    int2 rec = (c + lane < e1) ? edges[c + lane] : make_int2(0, 0);
    int cnt = e1 - c; if (cnt > 64) cnt = 64;
    int cend = (cnt + 15) & ~15;                // round to unroll width 16
    for (int u = 0; u < cend; u += 16) {
      __half2 v[16];
      float wg[16];
      #pragma unroll
      for (int q = 0; q < 16; ++q) {
        int s  = __builtin_amdgcn_readlane(rec.x, u + q);   // SGPR src id
        wg[q]  = __int_as_float(__builtin_amdgcn_readlane(rec.y, u + q));
        v[q]   = Hh[(size_t)s * 64 + lane];     // 4B fp16 gather
      }
      #pragma unroll
      for (int q = 0; q < 16; ++q) {
        float2 f = __half22float2(v[q]);
        ax += f.x * wg[q];
        ay += f.y * wg[q];
      }
    }
  }

  float2 b = ((const float2*)bias)[lane];
  float2 r;
  r.x = tanhf(ax + b.x);
  r.y = tanhf(ay + b.y);
  ((float2*)out)[(size_t)nid * 64 + lane] = r;
}

// ---------------------------------------------------------------- final linear(128->6)+tanh + mean pool
__global__ __launch_bounds__(256) void linpool(const float* __restrict__ H,
                                               const float* __restrict__ Wl,
                                               const float* __restrict__ bl,
                                               const int* __restrict__ batch,
                                               float* __restrict__ gsum,
                                               int* __restrict__ gcnt) {
  __shared__ float sW[128 * 6];
  __shared__ float sSum[NGR * 6];
  __shared__ int sCnt[NGR];
  int t = threadIdx.x;
  for (int i = t; i < 768; i += 256) sW[i] = Wl[i];
  for (int i = t; i < NGR * 6; i += 256) sSum[i] = 0.f;
  if (t < NGR) sCnt[t] = 0;
  __syncthreads();

  int gid = blockIdx.x * 256 + t;
  int node = gid >> 2;
  int seg = gid & 3;
  float a0 = 0, a1 = 0, a2 = 0, a3 = 0, a4 = 0, a5 = 0;
  if (node < NN) {
    const float4* H4 = (const float4*)(H + (size_t)node * 128 + seg * 32);
    #pragma unroll
    for (int q = 0; q < 8; ++q) {
      float4 hv = H4[q];
      float hvv[4] = {hv.x, hv.y, hv.z, hv.w};
      int kbase = seg * 32 + q * 4;
      #pragma unroll
      for (int kk = 0; kk < 4; ++kk) {
        float hx = hvv[kk];
        const float* wr = &sW[(kbase + kk) * 6];
        a0 += hx * wr[0]; a1 += hx * wr[1]; a2 += hx * wr[2];
        a3 += hx * wr[3]; a4 += hx * wr[4]; a5 += hx * wr[5];
      }
    }
  }
  a0 += __shfl_xor(a0, 1); a0 += __shfl_xor(a0, 2);
  a1 += __shfl_xor(a1, 1); a1 += __shfl_xor(a1, 2);
  a2 += __shfl_xor(a2, 1); a2 += __shfl_xor(a2, 2);
  a3 += __shfl_xor(a3, 1); a3 += __shfl_xor(a3, 2);
  a4 += __shfl_xor(a4, 1); a4 += __shfl_xor(a4, 2);
  a5 += __shfl_xor(a5, 1); a5 += __shfl_xor(a5, 2);
  if (node < NN && seg == 0) {
    int g = batch[node];
    atomicAdd(&sSum[g * 6 + 0], tanhf(a0 + bl[0]));
    atomicAdd(&sSum[g * 6 + 1], tanhf(a1 + bl[1]));
    atomicAdd(&sSum[g * 6 + 2], tanhf(a2 + bl[2]));
    atomicAdd(&sSum[g * 6 + 3], tanhf(a3 + bl[3]));
    atomicAdd(&sSum[g * 6 + 4], tanhf(a4 + bl[4]));
    atomicAdd(&sSum[g * 6 + 5], tanhf(a5 + bl[5]));
    atomicAdd(&sCnt[g], 1);
  }
  __syncthreads();
  for (int i = t; i < NGR * 6; i += 256) {
    int g = i / 6;
    if (sCnt[g] > 0) atomicAdd(&gsum[i], sSum[i]);
  }
  if (t < NGR && sCnt[t] > 0) atomicAdd(&gcnt[t], sCnt[t]);
}

__global__ void finalize(const float* __restrict__ gsum, const int* __restrict__ gcnt,
                         float* __restrict__ out) {
  int i = threadIdx.x;
  if (i < NGR * 6) {
    int g = i / 6;
    float c = (float)max(gcnt[g], 1);
    out[i] = gsum[i] / c;
  }
}

// ---------------------------------------------------------------- launch
extern "C" void kernel_launch(void* const* d_in, const int* in_sizes, int n_in,
                              void* d_out, int out_size, void* d_ws, size_t ws_size,
                              hipStream_t stream) {
  const float* x  = (const float*)d_in[0];
  const int*   ei = (const int*)d_in[1];     // JAX x64 disabled -> int32
  const int*   batch = (const int*)d_in[2];
  const float* W0 = (const float*)d_in[3];
  const float* b0 = (const float*)d_in[4];
  const float* W1 = (const float*)d_in[5];
  const float* b1 = (const float*)d_in[6];
  const float* W2 = (const float*)d_in[7];
  const float* b2 = (const float*)d_in[8];
  const float* Wl = (const float*)d_in[9];
  const float* bl = (const float*)d_in[10];
  float* out = (float*)d_out;

  const int* src = ei;
  const int* dst = ei + EE;

  char* w = (char*)d_ws;
  auto alloc = [&](size_t bytes) {
    void* p = (void*)w;
    w += (bytes + 255) & ~(size_t)255;
    return p;
  };
  float*  bufA   = (float*)alloc((size_t)NN * CH * 4);   // act ping
  float*  bufB   = (float*)alloc((size_t)NN * CH * 4);   // act pong
  __half* h16    = (__half*)alloc((size_t)NN * CH * 2);  // fp16 h (gather payload)
  int*    counts = (int*)alloc((size_t)NN * 4);
  int*    rowptr = (int*)alloc((size_t)(NN + 1) * 4);
  int*    fillptr= (int*)alloc((size_t)NN * 4);
  float*  dinv   = (float*)alloc((size_t)NN * 4);
  int2*   edges  = (int2*)alloc((size_t)EE * 8);
  int*    blockSums = (int*)alloc(256 * 4);
  float*  gsum   = (float*)alloc((NGR * 6 + NGR) * 4);
  int*    gcnt   = (int*)(gsum + NGR * 6);

  hipMemsetAsync(counts, 0, (size_t)NN * 4, stream);
  hipMemsetAsync(gsum, 0, (NGR * 6 + NGR) * 4, stream);

  // CSR build (reused for all 3 layers)
  count_deg<<<(EE + 255) / 256, 256, 0, stream>>>(dst, counts);
  scan_block_sums<<<NB, 256, 0, stream>>>(counts, blockSums);
  scan_final<<<NB, 256, 0, stream>>>(counts, blockSums, rowptr, fillptr, dinv);
  fill_csr<<<(EE + 255) / 256, 256, 0, stream>>>(src, dst, dinv, fillptr, edges);

  const int gemmGrid = (NN + 63) / 64;
  const int aggGrid  = (NN + 3) / 4;

  // layer 0: x -> h16 -> bufA (act)
  gemm128<<<gemmGrid, 256, 0, stream>>>(x, W0, h16);
  gcn_agg<<<aggGrid, 256, 0, stream>>>(h16, rowptr, edges, dinv, b0, bufA);
  // layer 1: bufA -> h16 -> bufB
  gemm128<<<gemmGrid, 256, 0, stream>>>(bufA, W1, h16);
  gcn_agg<<<aggGrid, 256, 0, stream>>>(h16, rowptr, edges, dinv, b1, bufB);
  // layer 2: bufB -> h16 -> bufA
  gemm128<<<gemmGrid, 256, 0, stream>>>(bufB, W2, h16);
  gcn_agg<<<aggGrid, 256, 0, stream>>>(h16, rowptr, edges, dinv, b2, bufA);

  // final linear + tanh + mean pool
  linpool<<<(NN * 4 + 255) / 256, 256, 0, stream>>>(bufA, Wl, bl, batch, gsum, gcnt);
  finalize<<<1, NGR * 6, 0, stream>>>(gsum, gcnt, out);
}

// Round 14
// 318.444 us; speedup vs baseline: 1.4106x; 1.1536x over previous
//
#include <hip/hip_runtime.h>
#include <hip/hip_fp16.h>

#define NN 50000
#define EE 800000
#define CH 128
#define NGR 64
#define NB 196        // ceil(NN/256)

typedef _Float16 half8 __attribute__((ext_vector_type(8)));
typedef float floatx4 __attribute__((ext_vector_type(4)));

// ---------------------------------------------------------------- CSR build
__global__ __launch_bounds__(256) void count_deg(const int* __restrict__ dst,
                                                 int* __restrict__ counts) {
  int e = blockIdx.x * 256 + threadIdx.x;
  if (e < EE) atomicAdd(&counts[dst[e]], 1);
}

__global__ __launch_bounds__(256) void scan_block_sums(const int* __restrict__ counts,
                                                       int* __restrict__ blockSums) {
  __shared__ int red[256];
  int t = threadIdx.x;
  int i = blockIdx.x * 256 + t;
  red[t] = (i < NN) ? counts[i] : 0;
  __syncthreads();
  for (int off = 128; off > 0; off >>= 1) {
    if (t < off) red[t] += red[t + off];
    __syncthreads();
  }
  if (t == 0) blockSums[blockIdx.x] = red[0];
}

// merged: per-block re-scan of the 196 block sums (saves a kernel)
__global__ __launch_bounds__(256) void scan_final(const int* __restrict__ counts,
                                                  const int* __restrict__ blockSums,
                                                  int* __restrict__ rowptr,
                                                  int* __restrict__ fillptr,
                                                  float* __restrict__ dinv) {
  __shared__ int tmp[256];
  __shared__ int sOffs[256];
  int t = threadIdx.x;
  int bs = (t < NB) ? blockSums[t] : 0;
  sOffs[t] = bs;
  __syncthreads();
  for (int off = 1; off < 256; off <<= 1) {
    int add = (t >= off) ? sOffs[t - off] : 0;
    __syncthreads();
    sOffs[t] += add;
    __syncthreads();
  }
  int myBlockOff = sOffs[blockIdx.x] - blockSums[blockIdx.x];

  int i = blockIdx.x * 256 + t;
  int v = (i < NN) ? counts[i] : 0;
  tmp[t] = v;
  __syncthreads();
  for (int off = 1; off < 256; off <<= 1) {
    int add = (t >= off) ? tmp[t - off] : 0;
    __syncthreads();
    tmp[t] += add;
    __syncthreads();
  }
  if (i < NN) {
    int ex = myBlockOff + tmp[t] - v;
    rowptr[i] = ex;
    fillptr[i] = ex;
    dinv[i] = rsqrtf((float)v + 1.0f);
  }
  if (i == 0) rowptr[NN] = EE;
}

// packed edge record: .x = src node, .y = bitcast(norm)
__global__ __launch_bounds__(256) void fill_csr(const int* __restrict__ src,
                                                const int* __restrict__ dst,
                                                const float* __restrict__ dinv,
                                                int* __restrict__ fillptr,
                                                int2* __restrict__ edges) {
  int e = blockIdx.x * 256 + threadIdx.x;
  if (e >= EE) return;
  int s = src[e], d = dst[e];
  int slot = atomicAdd(&fillptr[d], 1);
  edges[slot] = make_int2(s, __float_as_int(dinv[s] * dinv[d]));
}

// ---------------------------------------------------------------- W -> MFMA B-fragment prepack (fp16)
// B-frag layout for mfma_f32_16x16x32_f16: lane l holds 8 halfs of column
// col=ct*16+(l&15), k = ks*32 + (l>>4)*8 + j. Slot = (ks*8+ct)*64+lane.
// 3 weight matrices -> 3*2048 slots of half8 (96 KB total, L2-resident).
__global__ __launch_bounds__(256) void w2frag(const float* __restrict__ W0,
                                              const float* __restrict__ W1,
                                              const float* __restrict__ W2,
                                              half8* __restrict__ Wfrag) {
  int slot = blockIdx.x * 256 + threadIdx.x;
  if (slot >= 3 * 2048) return;
  const float* W = (slot < 2048) ? W0 : (slot < 4096) ? W1 : W2;
  int s = slot & 2047;
  int lane = s & 63;
  int fb = s >> 6;            // ks*8+ct
  int ks = fb >> 3, ct = fb & 7;
  int kg = lane >> 4;
  int col = ct * 16 + (lane & 15);
  int kbase = ks * 32 + kg * 8;
  half8 h;
  #pragma unroll
  for (int j = 0; j < 8; ++j) h[j] = (_Float16)W[(kbase + j) * CH + col];
  Wfrag[slot] = h;
}

// ---------------------------------------------------------------- MFMA GEMM 50000x128 @ 128x128, fp16 out
// Per wave: 16 rows x 128 cols. A-frags (4x half8) converted from fp32 X in
// registers; B-frags read directly from L2-resident Wfrag (coalesced 16B/lane).
// fp32 accumulate; epilogue rounds to fp16 h (identical rounding to validated
// fp16-h path). No LDS.
__global__ __launch_bounds__(256) void gemm_mfma(const float* __restrict__ X,
                                                 const half8* __restrict__ Wfrag,
                                                 __half* __restrict__ H16) {
  int t = threadIdx.x;
  int wave = t >> 6, lane = t & 63;
  int r0 = blockIdx.x * 64 + wave * 16;
  int row = r0 + (lane & 15);
  int kg = lane >> 4;
  bool valid = row < NN;
  const float4* Xr = (const float4*)(X + (size_t)row * CH);

  half8 a[4];
  #pragma unroll
  for (int ks = 0; ks < 4; ++ks) {
    float4 f0 = make_float4(0.f, 0.f, 0.f, 0.f), f1 = f0;
    if (valid) { f0 = Xr[ks * 8 + kg * 2]; f1 = Xr[ks * 8 + kg * 2 + 1]; }
    half8 h;
    h[0] = (_Float16)f0.x; h[1] = (_Float16)f0.y; h[2] = (_Float16)f0.z; h[3] = (_Float16)f0.w;
    h[4] = (_Float16)f1.x; h[5] = (_Float16)f1.y; h[6] = (_Float16)f1.z; h[7] = (_Float16)f1.w;
    a[ks] = h;
  }

  floatx4 acc[8];
  #pragma unroll
  for (int ct = 0; ct < 8; ++ct) acc[ct] = (floatx4){0.f, 0.f, 0.f, 0.f};

  #pragma unroll
  for (int ct = 0; ct < 8; ++ct) {
    #pragma unroll
    for (int ks = 0; ks < 4; ++ks) {
      half8 b = Wfrag[(ks * 8 + ct) * 64 + lane];
      acc[ct] = __builtin_amdgcn_mfma_f32_16x16x32_f16(a[ks], b, acc[ct], 0, 0, 0);
    }
  }

  // C/D: col = lane&15, row = (lane>>4)*4 + reg
  int orow = r0 + (lane >> 4) * 4;
  int ocol = lane & 15;
  #pragma unroll
  for (int ct = 0; ct < 8; ++ct) {
    #pragma unroll
    for (int r = 0; r < 4; ++r) {
      int rr = orow + r;
      if (rr < NN)
        H16[(size_t)rr * CH + ct * 16 + ocol] = __float2half(acc[ct][r]);
    }
  }
}

// ---------------------------------------------------------------- aggregation + self-loop + bias + tanh
// 1 wave per node: 64 lanes x half2. Cooperative edge-record load ->
// readlane-broadcast -> SGPR-base fp16 gathers (256B/row), 16-deep.
__global__ __launch_bounds__(256) void gcn_agg(const __half* __restrict__ H16,
                                               const int* __restrict__ rowptr,
                                               const int2* __restrict__ edges,
                                               const float* __restrict__ dinv,
                                               const float* __restrict__ bias,
                                               float* __restrict__ out) {
  int nid = blockIdx.x * 4 + (threadIdx.x >> 6);
  if (nid >= NN) return;
  int lane = threadIdx.x & 63;
  const __half2* Hh = (const __half2*)H16;      // 64 half2 per row
  float di = dinv[nid];
  float sw = di * di;
  float2 self = __half22float2(Hh[(size_t)nid * 64 + lane]);
  float ax = self.x * sw, ay = self.y * sw;

  int e0 = rowptr[nid], e1 = rowptr[nid + 1];
  for (int c = e0; c < e1; c += 64) {
    int2 rec = (c + lane < e1) ? edges[c + lane] : make_int2(0, 0);
    int cnt = e1 - c; if (cnt > 64) cnt = 64;
    int cend = (cnt + 15) & ~15;                // round to unroll width 16
    for (int u = 0; u < cend; u += 16) {
      __half2 v[16];
      float wg[16];
      #pragma unroll
      for (int q = 0; q < 16; ++q) {
        int s  = __builtin_amdgcn_readlane(rec.x, u + q);   // SGPR src id
        wg[q]  = __int_as_float(__builtin_amdgcn_readlane(rec.y, u + q));
        v[q]   = Hh[(size_t)s * 64 + lane];     // 4B fp16 gather
      }
      #pragma unroll
      for (int q = 0; q < 16; ++q) {
        float2 f = __half22float2(v[q]);
        ax += f.x * wg[q];
        ay += f.y * wg[q];
      }
    }
  }

  float2 b = ((const float2*)bias)[lane];
  float2 r;
  r.x = tanhf(ax + b.x);
  r.y = tanhf(ay + b.y);
  ((float2*)out)[(size_t)nid * 64 + lane] = r;
}

// ---------------------------------------------------------------- final linear(128->6)+tanh + mean pool
__global__ __launch_bounds__(256) void linpool(const float* __restrict__ H,
                                               const float* __restrict__ Wl,
                                               const float* __restrict__ bl,
                                               const int* __restrict__ batch,
                                               float* __restrict__ gsum,
                                               int* __restrict__ gcnt) {
  __shared__ float sW[128 * 6];
  __shared__ float sSum[NGR * 6];
  __shared__ int sCnt[NGR];
  int t = threadIdx.x;
  for (int i = t; i < 768; i += 256) sW[i] = Wl[i];
  for (int i = t; i < NGR * 6; i += 256) sSum[i] = 0.f;
  if (t < NGR) sCnt[t] = 0;
  __syncthreads();

  int gid = blockIdx.x * 256 + t;
  int node = gid >> 2;
  int seg = gid & 3;
  float a0 = 0, a1 = 0, a2 = 0, a3 = 0, a4 = 0, a5 = 0;
  if (node < NN) {
    const float4* H4 = (const float4*)(H + (size_t)node * 128 + seg * 32);
    #pragma unroll
    for (int q = 0; q < 8; ++q) {
      float4 hv = H4[q];
      float hvv[4] = {hv.x, hv.y, hv.z, hv.w};
      int kbase = seg * 32 + q * 4;
      #pragma unroll
      for (int kk = 0; kk < 4; ++kk) {
        float hx = hvv[kk];
        const float* wr = &sW[(kbase + kk) * 6];
        a0 += hx * wr[0]; a1 += hx * wr[1]; a2 += hx * wr[2];
        a3 += hx * wr[3]; a4 += hx * wr[4]; a5 += hx * wr[5];
      }
    }
  }
  a0 += __shfl_xor(a0, 1); a0 += __shfl_xor(a0, 2);
  a1 += __shfl_xor(a1, 1); a1 += __shfl_xor(a1, 2);
  a2 += __shfl_xor(a2, 1); a2 += __shfl_xor(a2, 2);
  a3 += __shfl_xor(a3, 1); a3 += __shfl_xor(a3, 2);
  a4 += __shfl_xor(a4, 1); a4 += __shfl_xor(a4, 2);
  a5 += __shfl_xor(a5, 1); a5 += __shfl_xor(a5, 2);
  if (node < NN && seg == 0) {
    int g = batch[node];
    atomicAdd(&sSum[g * 6 + 0], tanhf(a0 + bl[0]));
    atomicAdd(&sSum[g * 6 + 1], tanhf(a1 + bl[1]));
    atomicAdd(&sSum[g * 6 + 2], tanhf(a2 + bl[2]));
    atomicAdd(&sSum[g * 6 + 3], tanhf(a3 + bl[3]));
    atomicAdd(&sSum[g * 6 + 4], tanhf(a4 + bl[4]));
    atomicAdd(&sSum[g * 6 + 5], tanhf(a5 + bl[5]));
    atomicAdd(&sCnt[g], 1);
  }
  __syncthreads();
  for (int i = t; i < NGR * 6; i += 256) {
    int g = i / 6;
    if (sCnt[g] > 0) atomicAdd(&gsum[i], sSum[i]);
  }
  if (t < NGR && sCnt[t] > 0) atomicAdd(&gcnt[t], sCnt[t]);
}

__global__ void finalize(const float* __restrict__ gsum, const int* __restrict__ gcnt,
                         float* __restrict__ out) {
  int i = threadIdx.x;
  if (i < NGR * 6) {
    int g = i / 6;
    float c = (float)max(gcnt[g], 1);
    out[i] = gsum[i] / c;
  }
}

// ---------------------------------------------------------------- launch
extern "C" void kernel_launch(void* const* d_in, const int* in_sizes, int n_in,
                              void* d_out, int out_size, void* d_ws, size_t ws_size,
                              hipStream_t stream) {
  const float* x  = (const float*)d_in[0];
  const int*   ei = (const int*)d_in[1];     // JAX x64 disabled -> int32
  const int*   batch = (const int*)d_in[2];
  const float* W0 = (const float*)d_in[3];
  const float* b0 = (const float*)d_in[4];
  const float* W1 = (const float*)d_in[5];
  const float* b1 = (const float*)d_in[6];
  const float* W2 = (const float*)d_in[7];
  const float* b2 = (const float*)d_in[8];
  const float* Wl = (const float*)d_in[9];
  const float* bl = (const float*)d_in[10];
  float* out = (float*)d_out;

  const int* src = ei;
  const int* dst = ei + EE;

  char* w = (char*)d_ws;
  auto alloc = [&](size_t bytes) {
    void* p = (void*)w;
    w += (bytes + 255) & ~(size_t)255;
    return p;
  };
  float*  bufA   = (float*)alloc((size_t)NN * CH * 4);   // act ping (fp32)
  float*  bufB   = (float*)alloc((size_t)NN * CH * 4);   // act pong (fp32)
  __half* h16    = (__half*)alloc((size_t)NN * CH * 2);  // fp16 h (gather payload)
  half8*  wfrag  = (half8*)alloc((size_t)3 * 2048 * 16); // 3x W in B-frag order
  int*    counts = (int*)alloc((size_t)NN * 4);
  int*    rowptr = (int*)alloc((size_t)(NN + 1) * 4);
  int*    fillptr= (int*)alloc((size_t)NN * 4);
  float*  dinv   = (float*)alloc((size_t)NN * 4);
  int2*   edges  = (int2*)alloc((size_t)EE * 8);
  int*    blockSums = (int*)alloc(256 * 4);
  float*  gsum   = (float*)alloc((NGR * 6 + NGR) * 4);
  int*    gcnt   = (int*)(gsum + NGR * 6);

  hipMemsetAsync(counts, 0, (size_t)NN * 4, stream);
  hipMemsetAsync(gsum, 0, (NGR * 6 + NGR) * 4, stream);

  // CSR build (reused for all 3 layers) + weight prepack
  count_deg<<<(EE + 255) / 256, 256, 0, stream>>>(dst, counts);
  scan_block_sums<<<NB, 256, 0, stream>>>(counts, blockSums);
  scan_final<<<NB, 256, 0, stream>>>(counts, blockSums, rowptr, fillptr, dinv);
  fill_csr<<<(EE + 255) / 256, 256, 0, stream>>>(src, dst, dinv, fillptr, edges);
  w2frag<<<24, 256, 0, stream>>>(W0, W1, W2, wfrag);

  const int gemmGrid = (NN + 63) / 64;
  const int aggGrid  = (NN + 3) / 4;

  // layer 0: x -> h16 -> bufA (act)
  gemm_mfma<<<gemmGrid, 256, 0, stream>>>(x, wfrag, h16);
  gcn_agg<<<aggGrid, 256, 0, stream>>>(h16, rowptr, edges, dinv, b0, bufA);
  // layer 1: bufA -> h16 -> bufB
  gemm_mfma<<<gemmGrid, 256, 0, stream>>>(bufA, wfrag + 2048, h16);
  gcn_agg<<<aggGrid, 256, 0, stream>>>(h16, rowptr, edges, dinv, b1, bufB);
  // layer 2: bufB -> h16 -> bufA
  gemm_mfma<<<gemmGrid, 256, 0, stream>>>(bufB, wfrag + 4096, h16);
  gcn_agg<<<aggGrid, 256, 0, stream>>>(h16, rowptr, edges, dinv, b2, bufA);

  // final linear + tanh + mean pool
  linpool<<<(NN * 4 + 255) / 256, 256, 0, stream>>>(bufA, Wl, bl, batch, gsum, gcnt);
  finalize<<<1, NGR * 6, 0, stream>>>(gsum, gcnt, out);
}

// Round 15
// 316.173 us; speedup vs baseline: 1.4207x; 1.0072x over previous
//
#include <hip/hip_runtime.h>
#include <hip/hip_fp16.h>

#define NN 50000
#define EE 800000
#define CH 128
#define NGR 64
#define NB 196        // ceil(NN/256)
#define NXCD 8
#define PART 6250     // NN / NXCD

typedef _Float16 half8 __attribute__((ext_vector_type(8)));
typedef float floatx4 __attribute__((ext_vector_type(4)));

// ---------------------------------------------------------------- CSR build
__global__ __launch_bounds__(256) void count_deg(const int* __restrict__ dst,
                                                 int* __restrict__ counts) {
  int e = blockIdx.x * 256 + threadIdx.x;
  if (e < EE) atomicAdd(&counts[dst[e]], 1);
}

__global__ __launch_bounds__(256) void scan_block_sums(const int* __restrict__ counts,
                                                       int* __restrict__ blockSums) {
  __shared__ int red[256];
  int t = threadIdx.x;
  int i = blockIdx.x * 256 + t;
  red[t] = (i < NN) ? counts[i] : 0;
  __syncthreads();
  for (int off = 128; off > 0; off >>= 1) {
    if (t < off) red[t] += red[t + off];
    __syncthreads();
  }
  if (t == 0) blockSums[blockIdx.x] = red[0];
}

// merged: per-block re-scan of the 196 block sums (saves a kernel)
__global__ __launch_bounds__(256) void scan_final(const int* __restrict__ counts,
                                                  const int* __restrict__ blockSums,
                                                  int* __restrict__ rowptr,
                                                  int* __restrict__ fillptr,
                                                  float* __restrict__ dinv) {
  __shared__ int tmp[256];
  __shared__ int sOffs[256];
  int t = threadIdx.x;
  int bs = (t < NB) ? blockSums[t] : 0;
  sOffs[t] = bs;
  __syncthreads();
  for (int off = 1; off < 256; off <<= 1) {
    int add = (t >= off) ? sOffs[t - off] : 0;
    __syncthreads();
    sOffs[t] += add;
    __syncthreads();
  }
  int myBlockOff = sOffs[blockIdx.x] - blockSums[blockIdx.x];

  int i = blockIdx.x * 256 + t;
  int v = (i < NN) ? counts[i] : 0;
  tmp[t] = v;
  __syncthreads();
  for (int off = 1; off < 256; off <<= 1) {
    int add = (t >= off) ? tmp[t - off] : 0;
    __syncthreads();
    tmp[t] += add;
    __syncthreads();
  }
  if (i < NN) {
    int ex = myBlockOff + tmp[t] - v;
    rowptr[i] = ex;
    fillptr[i] = ex;
    dinv[i] = rsqrtf((float)v + 1.0f);
  }
  if (i == 0) rowptr[NN] = EE;
}

// XCD-partitioned CSR fill: partition p = blockIdx&7 (round-robin block->XCD)
// owns dst range [p*PART,(p+1)*PART). Each partition scans the full edge
// stream (reads x8 = 51MB, cheap) but writes ONLY its contiguous ~800KB slot
// range -> per-XCD L2 write locality, HBM writes 53MB -> ~7MB; fillptr
// atomics become XCD-local.
__global__ __launch_bounds__(256) void fill_csr(const int* __restrict__ src,
                                                const int* __restrict__ dst,
                                                const float* __restrict__ dinv,
                                                int* __restrict__ fillptr,
                                                int2* __restrict__ edges) {
  int p = blockIdx.x & (NXCD - 1);
  int e = (blockIdx.x >> 3) * 256 + threadIdx.x;
  if (e >= EE) return;
  int d = dst[e];
  if (d / PART != p) return;
  int s = src[e];
  int slot = atomicAdd(&fillptr[d], 1);
  edges[slot] = make_int2(s, __float_as_int(dinv[s] * dinv[d]));
}

// ---------------------------------------------------------------- W -> MFMA B-fragment prepack (fp16)
// B-frag layout for mfma_f32_16x16x32_f16: lane l holds 8 halfs of column
// col=ct*16+(l&15), k = ks*32 + (l>>4)*8 + j. Slot = (ks*8+ct)*64+lane.
// 3 weight matrices -> 3*2048 slots of half8 (96 KB total, L2-resident).
__global__ __launch_bounds__(256) void w2frag(const float* __restrict__ W0,
                                              const float* __restrict__ W1,
                                              const float* __restrict__ W2,
                                              half8* __restrict__ Wfrag) {
  int slot = blockIdx.x * 256 + threadIdx.x;
  if (slot >= 3 * 2048) return;
  const float* W = (slot < 2048) ? W0 : (slot < 4096) ? W1 : W2;
  int s = slot & 2047;
  int lane = s & 63;
  int fb = s >> 6;            // ks*8+ct
  int ks = fb >> 3, ct = fb & 7;
  int kg = lane >> 4;
  int col = ct * 16 + (lane & 15);
  int kbase = ks * 32 + kg * 8;
  half8 h;
  #pragma unroll
  for (int j = 0; j < 8; ++j) h[j] = (_Float16)W[(kbase + j) * CH + col];
  Wfrag[slot] = h;
}

// ---------------------------------------------------------------- MFMA GEMM 50000x128 @ 128x128, fp16 out
// Per wave: 16 rows x 128 cols. A-frags (4x half8) converted from fp32 X in
// registers; B-frags read directly from L2-resident Wfrag (coalesced 16B/lane).
// fp32 accumulate; epilogue rounds to fp16 h. No LDS.
__global__ __launch_bounds__(256) void gemm_mfma(const float* __restrict__ X,
                                                 const half8* __restrict__ Wfrag,
                                                 __half* __restrict__ H16) {
  int t = threadIdx.x;
  int wave = t >> 6, lane = t & 63;
  int r0 = blockIdx.x * 64 + wave * 16;
  int row = r0 + (lane & 15);
  int kg = lane >> 4;
  bool valid = row < NN;
  const float4* Xr = (const float4*)(X + (size_t)row * CH);

  half8 a[4];
  #pragma unroll
  for (int ks = 0; ks < 4; ++ks) {
    float4 f0 = make_float4(0.f, 0.f, 0.f, 0.f), f1 = f0;
    if (valid) { f0 = Xr[ks * 8 + kg * 2]; f1 = Xr[ks * 8 + kg * 2 + 1]; }
    half8 h;
    h[0] = (_Float16)f0.x; h[1] = (_Float16)f0.y; h[2] = (_Float16)f0.z; h[3] = (_Float16)f0.w;
    h[4] = (_Float16)f1.x; h[5] = (_Float16)f1.y; h[6] = (_Float16)f1.z; h[7] = (_Float16)f1.w;
    a[ks] = h;
  }

  floatx4 acc[8];
  #pragma unroll
  for (int ct = 0; ct < 8; ++ct) acc[ct] = (floatx4){0.f, 0.f, 0.f, 0.f};

  #pragma unroll
  for (int ct = 0; ct < 8; ++ct) {
    #pragma unroll
    for (int ks = 0; ks < 4; ++ks) {
      half8 b = Wfrag[(ks * 8 + ct) * 64 + lane];
      acc[ct] = __builtin_amdgcn_mfma_f32_16x16x32_f16(a[ks], b, acc[ct], 0, 0, 0);
    }
  }

  // C/D: col = lane&15, row = (lane>>4)*4 + reg
  int orow = r0 + (lane >> 4) * 4;
  int ocol = lane & 15;
  #pragma unroll
  for (int ct = 0; ct < 8; ++ct) {
    #pragma unroll
    for (int r = 0; r < 4; ++r) {
      int rr = orow + r;
      if (rr < NN)
        H16[(size_t)rr * CH + ct * 16 + ocol] = __float2half(acc[ct][r]);
    }
  }
}

// ---------------------------------------------------------------- aggregation + self-loop + bias + tanh
// 1 wave per node: 64 lanes x half2. Cooperative edge-record load ->
// readlane-broadcast -> SGPR-base fp16 gathers (256B/row), 16-deep.
__global__ __launch_bounds__(256) void gcn_agg(const __half* __restrict__ H16,
                                               const int* __restrict__ rowptr,
                                               const int2* __restrict__ edges,
                                               const float* __restrict__ dinv,
                                               const float* __restrict__ bias,
                                               float* __restrict__ out) {
  int nid = blockIdx.x * 4 + (threadIdx.x >> 6);
  if (nid >= NN) return;
  int lane = threadIdx.x & 63;
  const __half2* Hh = (const __half2*)H16;      // 64 half2 per row
  float di = dinv[nid];
  float sw = di * di;
  float2 self = __half22float2(Hh[(size_t)nid * 64 + lane]);
  float ax = self.x * sw, ay = self.y * sw;

  int e0 = rowptr[nid], e1 = rowptr[nid + 1];
  for (int c = e0; c < e1; c += 64) {
    int2 rec = (c + lane < e1) ? edges[c + lane] : make_int2(0, 0);
    int cnt = e1 - c; if (cnt > 64) cnt = 64;
    int cend = (cnt + 15) & ~15;                // round to unroll width 16
    for (int u = 0; u < cend; u += 16) {
      __half2 v[16];
      float wg[16];
      #pragma unroll
      for (int q = 0; q < 16; ++q) {
        int s  = __builtin_amdgcn_readlane(rec.x, u + q);   // SGPR src id
        wg[q]  = __int_as_float(__builtin_amdgcn_readlane(rec.y, u + q));
        v[q]   = Hh[(size_t)s * 64 + lane];     // 4B fp16 gather
      }
      #pragma unroll
      for (int q = 0; q < 16; ++q) {
        float2 f = __half22float2(v[q]);
        ax += f.x * wg[q];
        ay += f.y * wg[q];
      }
    }
  }

  float2 b = ((const float2*)bias)[lane];
  float2 r;
  r.x = tanhf(ax + b.x);
  r.y = tanhf(ay + b.y);
  ((float2*)out)[(size_t)nid * 64 + lane] = r;
}

// ---------------------------------------------------------------- final linear(128->6)+tanh + mean pool
__global__ __launch_bounds__(256) void linpool(const float* __restrict__ H,
                                               const float* __restrict__ Wl,
                                               const float* __restrict__ bl,
                                               const int* __restrict__ batch,
                                               float* __restrict__ gsum,
                                               int* __restrict__ gcnt) {
  __shared__ float sW[128 * 6];
  __shared__ float sSum[NGR * 6];
  __shared__ int sCnt[NGR];
  int t = threadIdx.x;
  for (int i = t; i < 768; i += 256) sW[i] = Wl[i];
  for (int i = t; i < NGR * 6; i += 256) sSum[i] = 0.f;
  if (t < NGR) sCnt[t] = 0;
  __syncthreads();

  int gid = blockIdx.x * 256 + t;
  int node = gid >> 2;
  int seg = gid & 3;
  float a0 = 0, a1 = 0, a2 = 0, a3 = 0, a4 = 0, a5 = 0;
  if (node < NN) {
    const float4* H4 = (const float4*)(H + (size_t)node * 128 + seg * 32);
    #pragma unroll
    for (int q = 0; q < 8; ++q) {
      float4 hv = H4[q];
      float hvv[4] = {hv.x, hv.y, hv.z, hv.w};
      int kbase = seg * 32 + q * 4;
      #pragma unroll
      for (int kk = 0; kk < 4; ++kk) {
        float hx = hvv[kk];
        const float* wr = &sW[(kbase + kk) * 6];
        a0 += hx * wr[0]; a1 += hx * wr[1]; a2 += hx * wr[2];
        a3 += hx * wr[3]; a4 += hx * wr[4]; a5 += hx * wr[5];
      }
    }
  }
  a0 += __shfl_xor(a0, 1); a0 += __shfl_xor(a0, 2);
  a1 += __shfl_xor(a1, 1); a1 += __shfl_xor(a1, 2);
  a2 += __shfl_xor(a2, 1); a2 += __shfl_xor(a2, 2);
  a3 += __shfl_xor(a3, 1); a3 += __shfl_xor(a3, 2);
  a4 += __shfl_xor(a4, 1); a4 += __shfl_xor(a4, 2);
  a5 += __shfl_xor(a5, 1); a5 += __shfl_xor(a5, 2);
  if (node < NN && seg == 0) {
    int g = batch[node];
    atomicAdd(&sSum[g * 6 + 0], tanhf(a0 + bl[0]));
    atomicAdd(&sSum[g * 6 + 1], tanhf(a1 + bl[1]));
    atomicAdd(&sSum[g * 6 + 2], tanhf(a2 + bl[2]));
    atomicAdd(&sSum[g * 6 + 3], tanhf(a3 + bl[3]));
    atomicAdd(&sSum[g * 6 + 4], tanhf(a4 + bl[4]));
    atomicAdd(&sSum[g * 6 + 5], tanhf(a5 + bl[5]));
    atomicAdd(&sCnt[g], 1);
  }
  __syncthreads();
  for (int i = t; i < NGR * 6; i += 256) {
    int g = i / 6;
    if (sCnt[g] > 0) atomicAdd(&gsum[i], sSum[i]);
  }
  if (t < NGR && sCnt[t] > 0) atomicAdd(&gcnt[t], sCnt[t]);
}

__global__ void finalize(const float* __restrict__ gsum, const int* __restrict__ gcnt,
                         float* __restrict__ out) {
  int i = threadIdx.x;
  if (i < NGR * 6) {
    int g = i / 6;
    float c = (float)max(gcnt[g], 1);
    out[i] = gsum[i] / c;
  }
}

// ---------------------------------------------------------------- launch
extern "C" void kernel_launch(void* const* d_in, const int* in_sizes, int n_in,
                              void* d_out, int out_size, void* d_ws, size_t ws_size,
                              hipStream_t stream) {
  const float* x  = (const float*)d_in[0];
  const int*   ei = (const int*)d_in[1];     // JAX x64 disabled -> int32
  const int*   batch = (const int*)d_in[2];
  const float* W0 = (const float*)d_in[3];
  const float* b0 = (const float*)d_in[4];
  const float* W1 = (const float*)d_in[5];
  const float* b1 = (const float*)d_in[6];
  const float* W2 = (const float*)d_in[7];
  const float* b2 = (const float*)d_in[8];
  const float* Wl = (const float*)d_in[9];
  const float* bl = (const float*)d_in[10];
  float* out = (float*)d_out;

  const int* src = ei;
  const int* dst = ei + EE;

  char* w = (char*)d_ws;
  auto alloc = [&](size_t bytes) {
    void* p = (void*)w;
    w += (bytes + 255) & ~(size_t)255;
    return p;
  };
  float*  bufA   = (float*)alloc((size_t)NN * CH * 4);   // act ping (fp32)
  float*  bufB   = (float*)alloc((size_t)NN * CH * 4);   // act pong (fp32)
  __half* h16    = (__half*)alloc((size_t)NN * CH * 2);  // fp16 h (gather payload)
  half8*  wfrag  = (half8*)alloc((size_t)3 * 2048 * 16); // 3x W in B-frag order
  int*    counts = (int*)alloc((size_t)NN * 4);
  int*    rowptr = (int*)alloc((size_t)(NN + 1) * 4);
  int*    fillptr= (int*)alloc((size_t)NN * 4);
  float*  dinv   = (float*)alloc((size_t)NN * 4);
  int2*   edges  = (int2*)alloc((size_t)EE * 8);
  int*    blockSums = (int*)alloc(256 * 4);
  float*  gsum   = (float*)alloc((NGR * 6 + NGR) * 4);
  int*    gcnt   = (int*)(gsum + NGR * 6);

  hipMemsetAsync(counts, 0, (size_t)NN * 4, stream);
  hipMemsetAsync(gsum, 0, (NGR * 6 + NGR) * 4, stream);

  // CSR build (reused for all 3 layers) + weight prepack
  count_deg<<<(EE + 255) / 256, 256, 0, stream>>>(dst, counts);
  scan_block_sums<<<NB, 256, 0, stream>>>(counts, blockSums);
  scan_final<<<NB, 256, 0, stream>>>(counts, blockSums, rowptr, fillptr, dinv);
  fill_csr<<<((EE + 255) / 256) * NXCD, 256, 0, stream>>>(src, dst, dinv, fillptr, edges);
  w2frag<<<24, 256, 0, stream>>>(W0, W1, W2, wfrag);

  const int gemmGrid = (NN + 63) / 64;
  const int aggGrid  = (NN + 3) / 4;

  // layer 0: x -> h16 -> bufA (act)
  gemm_mfma<<<gemmGrid, 256, 0, stream>>>(x, wfrag, h16);
  gcn_agg<<<aggGrid, 256, 0, stream>>>(h16, rowptr, edges, dinv, b0, bufA);
  // layer 1: bufA -> h16 -> bufB
  gemm_mfma<<<gemmGrid, 256, 0, stream>>>(bufA, wfrag + 2048, h16);
  gcn_agg<<<aggGrid, 256, 0, stream>>>(h16, rowptr, edges, dinv, b1, bufB);
  // layer 2: bufB -> h16 -> bufA
  gemm_mfma<<<gemmGrid, 256, 0, stream>>>(bufB, wfrag + 4096, h16);
  gcn_agg<<<aggGrid, 256, 0, stream>>>(h16, rowptr, edges, dinv, b2, bufA);

  // final linear + tanh + mean pool
  linpool<<<(NN * 4 + 255) / 256, 256, 0, stream>>>(bufA, Wl, bl, batch, gsum, gcnt);
  finalize<<<1, NGR * 6, 0, stream>>>(gsum, gcnt, out);
}

// Round 17
// 315.782 us; speedup vs baseline: 1.4225x; 1.0012x over previous
//
#include <hip/hip_runtime.h>
#include <hip/hip_fp16.h>

#define NN 50000
#define EE 800000
#define CH 128
#define NGR 64
#define NB 196        // ceil(NN/256)
#define NXCD 8
#define PART 6250     // NN / NXCD

typedef _Float16 half8 __attribute__((ext_vector_type(8)));
typedef float floatx4 __attribute__((ext_vector_type(4)));

// ---------------------------------------------------------------- CSR build
__global__ __launch_bounds__(256) void count_deg(const int* __restrict__ dst,
                                                 int* __restrict__ counts) {
  int e = blockIdx.x * 256 + threadIdx.x;
  if (e < EE) atomicAdd(&counts[dst[e]], 1);
}

__global__ __launch_bounds__(256) void scan_block_sums(const int* __restrict__ counts,
                                                       int* __restrict__ blockSums) {
  __shared__ int red[256];
  int t = threadIdx.x;
  int i = blockIdx.x * 256 + t;
  red[t] = (i < NN) ? counts[i] : 0;
  __syncthreads();
  for (int off = 128; off > 0; off >>= 1) {
    if (t < off) red[t] += red[t + off];
    __syncthreads();
  }
  if (t == 0) blockSums[blockIdx.x] = red[0];
}

// merged: per-block re-scan of the 196 block sums (saves a kernel)
__global__ __launch_bounds__(256) void scan_final(const int* __restrict__ counts,
                                                  const int* __restrict__ blockSums,
                                                  int* __restrict__ rowptr,
                                                  int* __restrict__ fillptr,
                                                  float* __restrict__ dinv) {
  __shared__ int tmp[256];
  __shared__ int sOffs[256];
  int t = threadIdx.x;
  int bs = (t < NB) ? blockSums[t] : 0;
  sOffs[t] = bs;
  __syncthreads();
  for (int off = 1; off < 256; off <<= 1) {
    int add = (t >= off) ? sOffs[t - off] : 0;
    __syncthreads();
    sOffs[t] += add;
    __syncthreads();
  }
  int myBlockOff = sOffs[blockIdx.x] - blockSums[blockIdx.x];

  int i = blockIdx.x * 256 + t;
  int v = (i < NN) ? counts[i] : 0;
  tmp[t] = v;
  __syncthreads();
  for (int off = 1; off < 256; off <<= 1) {
    int add = (t >= off) ? tmp[t - off] : 0;
    __syncthreads();
    tmp[t] += add;
    __syncthreads();
  }
  if (i < NN) {
    int ex = myBlockOff + tmp[t] - v;
    rowptr[i] = ex;
    fillptr[i] = ex;
    dinv[i] = rsqrtf((float)v + 1.0f);
  }
  if (i == 0) rowptr[NN] = EE;
}

// XCD-partitioned CSR fill (kept from R15; neutral vs R14)
__global__ __launch_bounds__(256) void fill_csr(const int* __restrict__ src,
                                                const int* __restrict__ dst,
                                                const float* __restrict__ dinv,
                                                int* __restrict__ fillptr,
                                                int2* __restrict__ edges) {
  int p = blockIdx.x & (NXCD - 1);
  int e = (blockIdx.x >> 3) * 256 + threadIdx.x;
  if (e >= EE) return;
  int d = dst[e];
  if (d / PART != p) return;
  int s = src[e];
  int slot = atomicAdd(&fillptr[d], 1);
  edges[slot] = make_int2(s, __float_as_int(dinv[s] * dinv[d]));
}

// ---------------------------------------------------------------- W -> MFMA B-fragment prepack (fp16)
__global__ __launch_bounds__(256) void w2frag(const float* __restrict__ W0,
                                              const float* __restrict__ W1,
                                              const float* __restrict__ W2,
                                              half8* __restrict__ Wfrag) {
  int slot = blockIdx.x * 256 + threadIdx.x;
  if (slot >= 3 * 2048) return;
  const float* W = (slot < 2048) ? W0 : (slot < 4096) ? W1 : W2;
  int s = slot & 2047;
  int lane = s & 63;
  int fb = s >> 6;            // ks*8+ct
  int ks = fb >> 3, ct = fb & 7;
  int kg = lane >> 4;
  int col = ct * 16 + (lane & 15);
  int kbase = ks * 32 + kg * 8;
  half8 h;
  #pragma unroll
  for (int j = 0; j < 8; ++j) h[j] = (_Float16)W[(kbase + j) * CH + col];
  Wfrag[slot] = h;
}

// ---------------------------------------------------------------- MFMA GEMM 50000x128 @ 128x128, int8+scale out
// Per wave: 16 rows x 128 cols. fp32 accumulate; epilogue quantizes each row
// to int8 with per-row scale (abs err <= 0.4% of rowmax — ~5x tighter than
// e4m3 which failed threshold by 3.4%). Payload stays 1B/channel (128B/row).
__global__ __launch_bounds__(256) void gemm_mfma(const float* __restrict__ X,
                                                 const half8* __restrict__ Wfrag,
                                                 signed char* __restrict__ H8,
                                                 float* __restrict__ rowscale) {
  int t = threadIdx.x;
  int wave = t >> 6, lane = t & 63;
  int r0 = blockIdx.x * 64 + wave * 16;
  int row = r0 + (lane & 15);
  int kg = lane >> 4;
  bool valid = row < NN;
  const float4* Xr = (const float4*)(X + (size_t)row * CH);

  half8 a[4];
  #pragma unroll
  for (int ks = 0; ks < 4; ++ks) {
    float4 f0 = make_float4(0.f, 0.f, 0.f, 0.f), f1 = f0;
    if (valid) { f0 = Xr[ks * 8 + kg * 2]; f1 = Xr[ks * 8 + kg * 2 + 1]; }
    half8 h;
    h[0] = (_Float16)f0.x; h[1] = (_Float16)f0.y; h[2] = (_Float16)f0.z; h[3] = (_Float16)f0.w;
    h[4] = (_Float16)f1.x; h[5] = (_Float16)f1.y; h[6] = (_Float16)f1.z; h[7] = (_Float16)f1.w;
    a[ks] = h;
  }

  floatx4 acc[8];
  #pragma unroll
  for (int ct = 0; ct < 8; ++ct) acc[ct] = (floatx4){0.f, 0.f, 0.f, 0.f};

  #pragma unroll
  for (int ct = 0; ct < 8; ++ct) {
    #pragma unroll
    for (int ks = 0; ks < 4; ++ks) {
      half8 b = Wfrag[(ks * 8 + ct) * 64 + lane];
      acc[ct] = __builtin_amdgcn_mfma_f32_16x16x32_f16(a[ks], b, acc[ct], 0, 0, 0);
    }
  }

  // C/D: col = lane&15, row = (lane>>4)*4 + reg. Row r's 128 elements live in
  // the 16 lanes sharing lane>>4 (8 ct each) -> intra-group shfl_xor max.
  int orow = r0 + (lane >> 4) * 4;
  int ocol = lane & 15;
  #pragma unroll
  for (int r = 0; r < 4; ++r) {
    float m = 0.f;
    #pragma unroll
    for (int ct = 0; ct < 8; ++ct) m = fmaxf(m, fabsf(acc[ct][r]));
    #pragma unroll
    for (int d = 1; d < 16; d <<= 1) m = fmaxf(m, __shfl_xor(m, d));
    int rr = orow + r;
    float inv = (m > 0.f) ? 127.f / m : 0.f;
    if (rr < NN) {
      #pragma unroll
      for (int ct = 0; ct < 8; ++ct)
        H8[(size_t)rr * CH + ct * 16 + ocol] =
            (signed char)__float2int_rn(acc[ct][r] * inv);
      if (ocol == 0) rowscale[rr] = m * (1.f / 127.f);
    }
  }
}

// ---------------------------------------------------------------- aggregation + self-loop + bias + tanh
// 1 wave per node: 64 lanes x 2 int8 channels (128B/row gather). Cooperative
// edge-record + rowscale load (scale folded into weight per-lane, L2-hit),
// readlane-broadcast -> SGPR-base gathers, 16-deep.
__global__ __launch_bounds__(256) void gcn_agg(const signed char* __restrict__ H8,
                                               const float* __restrict__ rowscale,
                                               const int* __restrict__ rowptr,
                                               const int2* __restrict__ edges,
                                               const float* __restrict__ dinv,
                                               const float* __restrict__ bias,
                                               float* __restrict__ out) {
  int nid = blockIdx.x * 4 + (threadIdx.x >> 6);
  if (nid >= NN) return;
  int lane = threadIdx.x & 63;
  const uchar2* Hb = (const uchar2*)H8;         // 64 byte-pairs per row
  float di = dinv[nid];
  float sw = di * di * rowscale[nid];
  uchar2 sb = Hb[(size_t)nid * 64 + lane];
  float ax = (float)(signed char)sb.x * sw;
  float ay = (float)(signed char)sb.y * sw;

  int e0 = rowptr[nid], e1 = rowptr[nid + 1];
  for (int c = e0; c < e1; c += 64) {
    int2 rec = (c + lane < e1) ? edges[c + lane] : make_int2(0, 0);
    // fold per-src int8 scale into the edge weight (rowscale is L2-resident;
    // masked lanes have rec.y == 0 -> wcomb 0)
    float wcomb = __int_as_float(rec.y) * rowscale[rec.x];
    int cnt = e1 - c; if (cnt > 64) cnt = 64;
    int cend = (cnt + 15) & ~15;                // round to unroll width 16
    for (int u = 0; u < cend; u += 16) {
      uchar2 v[16];
      float wg[16];
      #pragma unroll
      for (int q = 0; q < 16; ++q) {
        int s  = __builtin_amdgcn_readlane(rec.x, u + q);   // SGPR src id
        wg[q]  = __int_as_float(
                   __builtin_amdgcn_readlane(__float_as_int(wcomb), u + q));
        v[q]   = Hb[(size_t)s * 64 + lane];     // 2B int8 gather
      }
      #pragma unroll
      for (int q = 0; q < 16; ++q) {
        ax += (float)(signed char)v[q].x * wg[q];
        ay += (float)(signed char)v[q].y * wg[q];
      }
    }
  }

  float2 b = ((const float2*)bias)[lane];
  float2 r;
  r.x = tanhf(ax + b.x);
  r.y = tanhf(ay + b.y);
  ((float2*)out)[(size_t)nid * 64 + lane] = r;
}

// ---------------------------------------------------------------- final linear(128->6)+tanh + mean pool
__global__ __launch_bounds__(256) void linpool(const float* __restrict__ H,
                                               const float* __restrict__ Wl,
                                               const float* __restrict__ bl,
                                               const int* __restrict__ batch,
                                               float* __restrict__ gsum,
                                               int* __restrict__ gcnt) {
  __shared__ float sW[128 * 6];
  __shared__ float sSum[NGR * 6];
  __shared__ int sCnt[NGR];
  int t = threadIdx.x;
  for (int i = t; i < 768; i += 256) sW[i] = Wl[i];
  for (int i = t; i < NGR * 6; i += 256) sSum[i] = 0.f;
  if (t < NGR) sCnt[t] = 0;
  __syncthreads();

  int gid = blockIdx.x * 256 + t;
  int node = gid >> 2;
  int seg = gid & 3;
  float a0 = 0, a1 = 0, a2 = 0, a3 = 0, a4 = 0, a5 = 0;
  if (node < NN) {
    const float4* H4 = (const float4*)(H + (size_t)node * 128 + seg * 32);
    #pragma unroll
    for (int q = 0; q < 8; ++q) {
      float4 hv = H4[q];
      float hvv[4] = {hv.x, hv.y, hv.z, hv.w};
      int kbase = seg * 32 + q * 4;
      #pragma unroll
      for (int kk = 0; kk < 4; ++kk) {
        float hx = hvv[kk];
        const float* wr = &sW[(kbase + kk) * 6];
        a0 += hx * wr[0]; a1 += hx * wr[1]; a2 += hx * wr[2];
        a3 += hx * wr[3]; a4 += hx * wr[4]; a5 += hx * wr[5];
      }
    }
  }
  a0 += __shfl_xor(a0, 1); a0 += __shfl_xor(a0, 2);
  a1 += __shfl_xor(a1, 1); a1 += __shfl_xor(a1, 2);
  a2 += __shfl_xor(a2, 1); a2 += __shfl_xor(a2, 2);
  a3 += __shfl_xor(a3, 1); a3 += __shfl_xor(a3, 2);
  a4 += __shfl_xor(a4, 1); a4 += __shfl_xor(a4, 2);
  a5 += __shfl_xor(a5, 1); a5 += __shfl_xor(a5, 2);
  if (node < NN && seg == 0) {
    int g = batch[node];
    atomicAdd(&sSum[g * 6 + 0], tanhf(a0 + bl[0]));
    atomicAdd(&sSum[g * 6 + 1], tanhf(a1 + bl[1]));
    atomicAdd(&sSum[g * 6 + 2], tanhf(a2 + bl[2]));
    atomicAdd(&sSum[g * 6 + 3], tanhf(a3 + bl[3]));
    atomicAdd(&sSum[g * 6 + 4], tanhf(a4 + bl[4]));
    atomicAdd(&sSum[g * 6 + 5], tanhf(a5 + bl[5]));
    atomicAdd(&sCnt[g], 1);
  }
  __syncthreads();
  for (int i = t; i < NGR * 6; i += 256) {
    int g = i / 6;
    if (sCnt[g] > 0) atomicAdd(&gsum[i], sSum[i]);
  }
  if (t < NGR && sCnt[t] > 0) atomicAdd(&gcnt[t], sCnt[t]);
}

__global__ void finalize(const float* __restrict__ gsum, const int* __restrict__ gcnt,
                         float* __restrict__ out) {
  int i = threadIdx.x;
  if (i < NGR * 6) {
    int g = i / 6;
    float c = (float)max(gcnt[g], 1);
    out[i] = gsum[i] / c;
  }
}

// ---------------------------------------------------------------- launch
extern "C" void kernel_launch(void* const* d_in, const int* in_sizes, int n_in,
                              void* d_out, int out_size, void* d_ws, size_t ws_size,
                              hipStream_t stream) {
  const float* x  = (const float*)d_in[0];
  const int*   ei = (const int*)d_in[1];     // JAX x64 disabled -> int32
  const int*   batch = (const int*)d_in[2];
  const float* W0 = (const float*)d_in[3];
  const float* b0 = (const float*)d_in[4];
  const float* W1 = (const float*)d_in[5];
  const float* b1 = (const float*)d_in[6];
  const float* W2 = (const float*)d_in[7];
  const float* b2 = (const float*)d_in[8];
  const float* Wl = (const float*)d_in[9];
  const float* bl = (const float*)d_in[10];
  float* out = (float*)d_out;

  const int* src = ei;
  const int* dst = ei + EE;

  char* w = (char*)d_ws;
  auto alloc = [&](size_t bytes) {
    void* p = (void*)w;
    w += (bytes + 255) & ~(size_t)255;
    return p;
  };
  float*  bufA   = (float*)alloc((size_t)NN * CH * 4);   // act ping (fp32)
  float*  bufB   = (float*)alloc((size_t)NN * CH * 4);   // act pong (fp32)
  signed char* h8 = (signed char*)alloc((size_t)NN * CH); // int8 h (gather payload)
  float*  rowscale = (float*)alloc((size_t)NN * 4);      // per-row int8 scale
  half8*  wfrag  = (half8*)alloc((size_t)3 * 2048 * 16); // 3x W in B-frag order
  int*    counts = (int*)alloc((size_t)NN * 4);
  int*    rowptr = (int*)alloc((size_t)(NN + 1) * 4);
  int*    fillptr= (int*)alloc((size_t)NN * 4);
  float*  dinv   = (float*)alloc((size_t)NN * 4);
  int2*   edges  = (int2*)alloc((size_t)EE * 8);
  int*    blockSums = (int*)alloc(256 * 4);
  float*  gsum   = (float*)alloc((NGR * 6 + NGR) * 4);
  int*    gcnt   = (int*)(gsum + NGR * 6);

  hipMemsetAsync(counts, 0, (size_t)NN * 4, stream);
  hipMemsetAsync(gsum, 0, (NGR * 6 + NGR) * 4, stream);

  // CSR build (reused for all 3 layers) + weight prepack
  count_deg<<<(EE + 255) / 256, 256, 0, stream>>>(dst, counts);
  scan_block_sums<<<NB, 256, 0, stream>>>(counts, blockSums);
  scan_final<<<NB, 256, 0, stream>>>(counts, blockSums, rowptr, fillptr, dinv);
  fill_csr<<<((EE + 255) / 256) * NXCD, 256, 0, stream>>>(src, dst, dinv, fillptr, edges);
  w2frag<<<24, 256, 0, stream>>>(W0, W1, W2, wfrag);

  const int gemmGrid = (NN + 63) / 64;
  const int aggGrid  = (NN + 3) / 4;

  // layer 0: x -> h8(+scale) -> bufA (act)
  gemm_mfma<<<gemmGrid, 256, 0, stream>>>(x, wfrag, h8, rowscale);
  gcn_agg<<<aggGrid, 256, 0, stream>>>(h8, rowscale, rowptr, edges, dinv, b0, bufA);
  // layer 1: bufA -> h8 -> bufB
  gemm_mfma<<<gemmGrid, 256, 0, stream>>>(bufA, wfrag + 2048, h8, rowscale);
  gcn_agg<<<aggGrid, 256, 0, stream>>>(h8, rowscale, rowptr, edges, dinv, b1, bufB);
  // layer 2: bufB -> h8 -> bufA
  gemm_mfma<<<gemmGrid, 256, 0, stream>>>(bufB, wfrag + 4096, h8, rowscale);
  gcn_agg<<<aggGrid, 256, 0, stream>>>(h8, rowscale, rowptr, edges, dinv, b2, bufA);

  // final linear + tanh + mean pool
  linpool<<<(NN * 4 + 255) / 256, 256, 0, stream>>>(bufA, Wl, bl, batch, gsum, gcnt);
  finalize<<<1, NGR * 6, 0, stream>>>(gsum, gcnt, out);
}